// Round 1
// baseline (99.779 us; speedup 1.0000x reference)
//
#include <hip/hip_runtime.h>
#include <math.h>

#define B_ROWS 16384
#define C_COLS 4096

// One block (256 threads = 4 waves) per row.
// Single pass over HBM: p kept in 16 registers/thread for the exp pass.
__global__ __launch_bounds__(256) void ce_rows_kernel(
    const float* __restrict__ p, const float* __restrict__ pai,
    float* __restrict__ ce_out) {
  const int row = blockIdx.x;
  const size_t base = (size_t)row * C_COLS;
  const float4* p4 = reinterpret_cast<const float4*>(p + base);
  const float4* q4 = reinterpret_cast<const float4*>(pai + base);
  const int t = threadIdx.x;          // 0..255
  const int wave = t >> 6;            // 0..3
  const int lane = t & 63;            // wave64

  float4 pv[4];
  float tmax = -INFINITY;
  float tdot = 0.f, tpsum = 0.f;
#pragma unroll
  for (int k = 0; k < 4; ++k) {
    float4 a = p4[k * 256 + t];       // fully coalesced: lanes 16B apart
    float4 b = q4[k * 256 + t];
    pv[k] = a;
    tmax = fmaxf(tmax, fmaxf(fmaxf(a.x, a.y), fmaxf(a.z, a.w)));
    tdot = fmaf(a.x, b.x, fmaf(a.y, b.y, fmaf(a.z, b.z, fmaf(a.w, b.w, tdot))));
    tpsum += (b.x + b.y) + (b.z + b.w);
  }

  // wave-level max reduce (64 lanes)
#pragma unroll
  for (int i = 1; i < 64; i <<= 1)
    tmax = fmaxf(tmax, __shfl_xor(tmax, i, 64));

  __shared__ float smax[4];
  if (lane == 0) smax[wave] = tmax;
  __syncthreads();
  const float m = fmaxf(fmaxf(smax[0], smax[1]), fmaxf(smax[2], smax[3]));

  // exp pass from registers (no HBM re-read)
  float tsum = 0.f;
#pragma unroll
  for (int k = 0; k < 4; ++k) {
    tsum += __expf(pv[k].x - m) + __expf(pv[k].y - m) +
            __expf(pv[k].z - m) + __expf(pv[k].w - m);
  }

#pragma unroll
  for (int i = 1; i < 64; i <<= 1) {
    tsum  += __shfl_xor(tsum,  i, 64);
    tdot  += __shfl_xor(tdot,  i, 64);
    tpsum += __shfl_xor(tpsum, i, 64);
  }

  __shared__ float ssum[4], sdot[4], spsum[4];
  if (lane == 0) { ssum[wave] = tsum; sdot[wave] = tdot; spsum[wave] = tpsum; }
  __syncthreads();
  if (t == 0) {
    const float S = (ssum[0] + ssum[1]) + (ssum[2] + ssum[3]);
    const float D = (sdot[0] + sdot[1]) + (sdot[2] + sdot[3]);
    const float P = (spsum[0] + spsum[1]) + (spsum[2] + spsum[3]);
    const float lse = m + __logf(S);
    ce_out[row] = lse * P - D;   // per-row CE: lse*sum(pai) - dot(pai,p)
  }
}

// Deterministic final reduction: 1 block, 1024 threads (16 waves).
__global__ __launch_bounds__(1024) void finalize_kernel(
    const float* __restrict__ ce, const float* __restrict__ v,
    const float* __restrict__ z, float* __restrict__ out) {
  const int t = threadIdx.x;
  const int lane = t & 63, wave = t >> 6;
  float lce = 0.f, lmse = 0.f;
  for (int i = t; i < B_ROWS; i += 1024) {
    lce += ce[i];
    const float d = z[i] - v[i];
    lmse = fmaf(d, d, lmse);
  }
#pragma unroll
  for (int i = 1; i < 64; i <<= 1) {
    lce  += __shfl_xor(lce,  i, 64);
    lmse += __shfl_xor(lmse, i, 64);
  }
  __shared__ float sce[16], smse[16];
  if (lane == 0) { sce[wave] = lce; smse[wave] = lmse; }
  __syncthreads();
  if (t == 0) {
    float CE = 0.f, MSE = 0.f;
    for (int w = 0; w < 16; ++w) { CE += sce[w]; MSE += smse[w]; }
    out[0] = MSE / (float)B_ROWS + CE / 20.0f;
  }
}

extern "C" void kernel_launch(void* const* d_in, const int* in_sizes, int n_in,
                              void* d_out, int out_size, void* d_ws, size_t ws_size,
                              hipStream_t stream) {
  const float* p   = (const float*)d_in[0];
  const float* v   = (const float*)d_in[1];
  const float* z   = (const float*)d_in[2];
  const float* pai = (const float*)d_in[3];
  float* ce  = (float*)d_ws;              // 16384 floats = 64 KiB scratch
  float* out = (float*)d_out;

  ce_rows_kernel<<<B_ROWS, 256, 0, stream>>>(p, pai, ce);
  finalize_kernel<<<1, 1024, 0, stream>>>(ce, v, z, out);
}